// Round 1
// baseline (361.425 us; speedup 1.0000x reference)
//
#include <hip/hip_runtime.h>
#include <hip/hip_bf16.h>
#include <math.h>

#define F_IN  32
#define F_HID 32
#define F_OUT 16

// ---------------- degree ----------------
__global__ void k_init_deg(int* __restrict__ deg, int n) {
    int i = blockIdx.x * 256 + threadIdx.x;
    if (i < n) deg[i] = 1;  // self-loop contributes 1 to every node's degree
}

__global__ void k_count_deg(const int* __restrict__ ei, int ne, int* __restrict__ deg) {
    int e = blockIdx.x * 256 + threadIdx.x;
    if (e < ne) atomicAdd(&deg[ei[ne + e]], 1);  // dst row
}

__global__ void k_dinv(const int* __restrict__ deg, float* __restrict__ dinv, int n) {
    int i = blockIdx.x * 256 + threadIdx.x;
    if (i < n) dinv[i] = rsqrtf((float)deg[i]);
}

// ---------------- layer 1: g1 = (x @ W1) * dinv ; s1 = g1 (self-loop seed) ----
__launch_bounds__(256)
__global__ void k_mm1(const float* __restrict__ x, const float* __restrict__ W1,
                      const float* __restrict__ dinv,
                      float* __restrict__ g1, float* __restrict__ s1, int n) {
    __shared__ float Ws[F_IN * F_HID];   // 32x32
    __shared__ float xs[8 * F_IN];       // 8 nodes per block
    int t = threadIdx.x;
    for (int i = t; i < F_IN * F_HID; i += 256) Ws[i] = W1[i];
    int nl = t >> 5, c = t & 31;
    int node = blockIdx.x * 8 + nl;
    if (node < n) xs[t] = x[(size_t)node * F_IN + c];
    __syncthreads();
    if (node >= n) return;
    float sum = 0.f;
    #pragma unroll
    for (int k = 0; k < F_IN; ++k) sum += xs[nl * F_IN + k] * Ws[k * F_HID + c];
    float g = sum * dinv[node];
    size_t o = (size_t)node * F_HID + c;
    g1[o] = g;
    s1[o] = g;
}

// ---------------- edge scatter, 32 channels ----------------
__global__ void k_edge32(const int* __restrict__ ei, int ne,
                         const float* __restrict__ g, float* __restrict__ s) {
    int gid = blockIdx.x * 256 + threadIdx.x;
    int e = gid >> 5, c = gid & 31;
    if (e >= ne) return;
    int sn = ei[e], dn = ei[ne + e];
    atomicAdd(&s[(size_t)dn * 32 + c], g[(size_t)sn * 32 + c]);
}

// ---------------- mid: h = tanh(dinv*s1 + b1); g2 = (h @ W2)*dinv; s2 = g2 ----
__launch_bounds__(256)
__global__ void k_mid(const float* __restrict__ s1, const float* __restrict__ dinv,
                      const float* __restrict__ b1, const float* __restrict__ W2,
                      float* __restrict__ g2, float* __restrict__ s2, int n) {
    __shared__ float Ws[F_HID * F_OUT];  // 32x16
    __shared__ float hs[16 * F_HID];     // 16 nodes per block
    int t = threadIdx.x;
    for (int i = t; i < F_HID * F_OUT; i += 256) Ws[i] = W2[i];
    int node0 = blockIdx.x * 16;
    for (int i = t; i < 16 * F_HID; i += 256) {
        int nl = i >> 5, k = i & 31;
        int node = node0 + nl;
        float v = 0.f;
        if (node < n) v = tanhf(dinv[node] * s1[(size_t)node * F_HID + k] + b1[k]);
        hs[i] = v;
    }
    __syncthreads();
    int nl = t >> 4, c = t & 15;
    int node = node0 + nl;
    if (node >= n) return;
    float sum = 0.f;
    #pragma unroll
    for (int k = 0; k < F_HID; ++k) sum += hs[nl * F_HID + k] * Ws[k * F_OUT + c];
    float g = sum * dinv[node];
    size_t o = (size_t)node * F_OUT + c;
    g2[o] = g;
    s2[o] = g;
}

// ---------------- edge scatter, 16 channels ----------------
__global__ void k_edge16(const int* __restrict__ ei, int ne,
                         const float* __restrict__ g, float* __restrict__ s) {
    int gid = blockIdx.x * 256 + threadIdx.x;
    int e = gid >> 4, c = gid & 15;
    if (e >= ne) return;
    int sn = ei[e], dn = ei[ne + e];
    atomicAdd(&s[(size_t)dn * 16 + c], g[(size_t)sn * 16 + c]);
}

// ---------------- finish: out = dinv*s2 + b2 ; log_softmax ----------------
__global__ void k_final(const float* __restrict__ s2, const float* __restrict__ dinv,
                        const float* __restrict__ b2,
                        float* __restrict__ out_h, float* __restrict__ out_ls, int n) {
    int i = blockIdx.x * 256 + threadIdx.x;
    if (i >= n) return;
    float di = dinv[i];
    float v[F_OUT];
    float m = -INFINITY;
    #pragma unroll
    for (int c = 0; c < F_OUT; ++c) {
        v[c] = di * s2[(size_t)i * F_OUT + c] + b2[c];
        m = fmaxf(m, v[c]);
    }
    float sum = 0.f;
    #pragma unroll
    for (int c = 0; c < F_OUT; ++c) sum += expf(v[c] - m);
    float l = logf(sum) + m;
    #pragma unroll
    for (int c = 0; c < F_OUT; ++c) {
        out_h[(size_t)i * F_OUT + c] = v[c];
        out_ls[(size_t)i * F_OUT + c] = v[c] - l;
    }
}

extern "C" void kernel_launch(void* const* d_in, const int* in_sizes, int n_in,
                              void* d_out, int out_size, void* d_ws, size_t ws_size,
                              hipStream_t stream) {
    const float* x  = (const float*)d_in[0];
    const int*   ei = (const int*)d_in[1];   // [2, E] flat: [0:E]=src, [E:2E]=dst
    const float* W1 = (const float*)d_in[2];
    const float* b1 = (const float*)d_in[3];
    const float* W2 = (const float*)d_in[4];
    const float* b2 = (const float*)d_in[5];

    int n  = in_sizes[0] / F_IN;
    int ne = in_sizes[1] / 2;

    float* out_h  = (float*)d_out;
    float* out_ls = out_h + (size_t)n * F_OUT;

    char* p = (char*)d_ws;
    int*   deg  = (int*)p;   p += (size_t)n * sizeof(int);
    float* dinv = (float*)p; p += (size_t)n * sizeof(float);
    float* g1   = (float*)p; p += (size_t)n * F_HID * sizeof(float);
    float* s1   = (float*)p; p += (size_t)n * F_HID * sizeof(float);
    float* g2   = (float*)p; p += (size_t)n * F_OUT * sizeof(float);
    float* s2   = (float*)p; p += (size_t)n * F_OUT * sizeof(float);

    k_init_deg<<<(n + 255) / 256, 256, 0, stream>>>(deg, n);
    k_count_deg<<<(ne + 255) / 256, 256, 0, stream>>>(ei, ne, deg);
    k_dinv<<<(n + 255) / 256, 256, 0, stream>>>(deg, dinv, n);

    k_mm1<<<(n + 7) / 8, 256, 0, stream>>>(x, W1, dinv, g1, s1, n);

    long tot1 = (long)ne * 32;
    k_edge32<<<(int)((tot1 + 255) / 256), 256, 0, stream>>>(ei, ne, g1, s1);

    k_mid<<<(n + 15) / 16, 256, 0, stream>>>(s1, dinv, b1, W2, g2, s2, n);

    long tot2 = (long)ne * 16;
    k_edge16<<<(int)((tot2 + 255) / 256), 256, 0, stream>>>(ei, ne, g2, s2);

    k_final<<<(n + 255) / 256, 256, 0, stream>>>(s2, dinv, b2, out_h, out_ls, n);
}